// Round 6
// baseline (227.242 us; speedup 1.0000x reference)
//
#include <hip/hip_runtime.h>
#include <math.h>

#define NPTS 300000
#define K 64
#define P 32
#define DETC 1e-16f
// one accumulator copy: [0,64) N_k | [64,128) S_k | [128,2176) M[d][k]
#define WS_FLOATS (K + K + K * P)
// striped copies to avoid same-line atomic serialization across 8 XCDs
#define NCOPIES 32

#define NTHREADS 256
#define WPB (NTHREADS / 64)                    // 4 waves / block
#define TILE 64                                // points per wave
#define NTILES ((NPTS + TILE - 1) / TILE)      // 4688
#define NBLOCKS ((NTILES + WPB - 1) / WPB)     // 1172

// ---- DPP helpers: sum across 64 lanes with VALU-only latency ----
#define DPP_ADD(v, ctrl)                                                     \
    v += __int_as_float(__builtin_amdgcn_update_dpp(                         \
        0, __float_as_int(v), (ctrl), 0xF, 0xF, true))

__device__ __forceinline__ float rl(float x, int lane) {
    return __int_as_float(__builtin_amdgcn_readlane(__float_as_int(x), lane));
}

__global__ __launch_bounds__(NTHREADS, 4) void em_pass(
    const float* __restrict__ mu_phi,
    const float* __restrict__ log_cov_phi,
    const float* __restrict__ pi_k,
    const float* __restrict__ mu_k,
    const float* __restrict__ log_cov_k,
    float* __restrict__ gamma_out,
    float* __restrict__ out_tail,   // pi_new | mu_new | log_cov_new
    float* __restrict__ ws)
{
    const int lane = threadIdx.x & 63;                 // = cluster index
    const int wave = threadIdx.x >> 6;
    const int gw = __builtin_amdgcn_readfirstlane(blockIdx.x * WPB + wave); // tile id

    // ---- per-lane cluster constants (icov folded into mk2) ----
    const float lck  = log_cov_k[lane];
    const float icov = __expf(-lck);
    const float pik  = pi_k[lane];

    float mk2[P];
    float n2k = 0.f;
#pragma unroll
    for (int d = 0; d < P; ++d) {
        const float m = mu_k[lane * P + d];
        mk2[d] = icov * m;
        n2k = fmaf(m, m, n2k);
    }
    // exponent = sum_d row[d]*mk2[d] - 0.5*icov*u + 16*lcp - Ak
    const float Ak     = 0.5f * (32.f * lck - 32.f + icov * n2k) - __logf(pik);
    const float negAk  = -Ak;
    const float nhicov = -0.5f * icov;

    float accN = 0.f, accS = 0.f;
    float accM[P];
#pragma unroll
    for (int d = 0; d < P; ++d) accM[d] = 0.f;

    const int start = gw * TILE;
    const int cnt   = (NPTS - start < TILE) ? (NPTS - start) : TILE;

    // ---- residency phase: lane l holds row (start+l) in 8 float4 VGPRs for
    //      the whole tile. Clamped index for the ragged tail keeps registers
    //      defined (never readlane'd beyond p<cnt). Coalesced-ish: the wave
    //      reads one contiguous 8KB span, every byte used once. ----
    const int ridx = start + ((lane < cnt) ? lane : 0);
    const float4* r4p = reinterpret_cast<const float4*>(mu_phi + (size_t)ridx * P);
    float4 c0 = r4p[0], c1 = r4p[1], c2 = r4p[2], c3 = r4p[3];
    float4 c4 = r4p[4], c5 = r4p[5], c6 = r4p[6], c7 = r4p[7];

    float n2 = 0.f;
#define N2ACC(q) n2 = fmaf(q.x,q.x,n2); n2 = fmaf(q.y,q.y,n2); \
                 n2 = fmaf(q.z,q.z,n2); n2 = fmaf(q.w,q.w,n2)
    N2ACC(c0); N2ACC(c1); N2ACC(c2); N2ACC(c3);
    N2ACC(c4); N2ACC(c5); N2ACC(c6); N2ACC(c7);
#undef N2ACC
    const float lcp  = log_cov_phi[ridx];
    const float u_v  = fmaf(32.f, __expf(lcp), n2);   // P*e^lcp + ||phi||^2
    const float bl_v = 16.f * lcp;

    // ---- per-point phase: lane = cluster. Row p is broadcast from lane p's
    //      registers via v_readlane (VALU pipe, uniform->SGPR results).
    //      ZERO memory reads in this loop: no s_load, no LDS, no VMEM-read.
#pragma unroll 2
    for (int p = 0; p < cnt; ++p) {
        const int i = start + p;
        const float u_s  = rl(u_v, p);
        const float bl_s = rl(bl_v, p);

        // broadcast row p: 32 readlanes -> uniform (SGPR) values
        const float s00 = rl(c0.x, p), s01 = rl(c0.y, p), s02 = rl(c0.z, p), s03 = rl(c0.w, p);
        const float s04 = rl(c1.x, p), s05 = rl(c1.y, p), s06 = rl(c1.z, p), s07 = rl(c1.w, p);
        const float s08 = rl(c2.x, p), s09 = rl(c2.y, p), s10 = rl(c2.z, p), s11 = rl(c2.w, p);
        const float s12 = rl(c3.x, p), s13 = rl(c3.y, p), s14 = rl(c3.z, p), s15 = rl(c3.w, p);
        const float s16 = rl(c4.x, p), s17 = rl(c4.y, p), s18 = rl(c4.z, p), s19 = rl(c4.w, p);
        const float s20 = rl(c5.x, p), s21 = rl(c5.y, p), s22 = rl(c5.z, p), s23 = rl(c5.w, p);
        const float s24 = rl(c6.x, p), s25 = rl(c6.y, p), s26 = rl(c6.z, p), s27 = rl(c6.w, p);
        const float s28 = rl(c7.x, p), s29 = rl(c7.y, p), s30 = rl(c7.z, p), s31 = rl(c7.w, p);

        // 4 independent FMA chains (8 deep each); row operand is SGPR (1/instr)
        float d0 = 0.f, d1 = 0.f, d2 = 0.f, d3 = 0.f;
        d0 = fmaf(s00, mk2[0],  d0); d1 = fmaf(s01, mk2[1],  d1);
        d2 = fmaf(s02, mk2[2],  d2); d3 = fmaf(s03, mk2[3],  d3);
        d0 = fmaf(s04, mk2[4],  d0); d1 = fmaf(s05, mk2[5],  d1);
        d2 = fmaf(s06, mk2[6],  d2); d3 = fmaf(s07, mk2[7],  d3);
        d0 = fmaf(s08, mk2[8],  d0); d1 = fmaf(s09, mk2[9],  d1);
        d2 = fmaf(s10, mk2[10], d2); d3 = fmaf(s11, mk2[11], d3);
        d0 = fmaf(s12, mk2[12], d0); d1 = fmaf(s13, mk2[13], d1);
        d2 = fmaf(s14, mk2[14], d2); d3 = fmaf(s15, mk2[15], d3);
        d0 = fmaf(s16, mk2[16], d0); d1 = fmaf(s17, mk2[17], d1);
        d2 = fmaf(s18, mk2[18], d2); d3 = fmaf(s19, mk2[19], d3);
        d0 = fmaf(s20, mk2[20], d0); d1 = fmaf(s21, mk2[21], d1);
        d2 = fmaf(s22, mk2[22], d2); d3 = fmaf(s23, mk2[23], d3);
        d0 = fmaf(s24, mk2[24], d0); d1 = fmaf(s25, mk2[25], d1);
        d2 = fmaf(s26, mk2[26], d2); d3 = fmaf(s27, mk2[27], d3);
        d0 = fmaf(s28, mk2[28], d0); d1 = fmaf(s29, mk2[29], d1);
        d2 = fmaf(s30, mk2[30], d2); d3 = fmaf(s31, mk2[31], d3);
        const float dot = (d0 + d1) + (d2 + d3);

        // arg = dot + (nhicov*u - Ak) + 16*lcp
        const float tpart = fmaf(nhicov, u_s, negAk);
        const float w = __expf((dot + tpart) + bl_s);

        // wave-64 sum via DPP (VALU) + readlane combine
        float v = w;
        DPP_ADD(v, 0xB1);   // quad_perm xor1
        DPP_ADD(v, 0x4E);   // quad_perm xor2
        DPP_ADD(v, 0x128);  // row_ror:8
        DPP_ADD(v, 0x124);  // row_ror:4  -> each lane = its 16-row sum
        const float sum = (rl(v, 0) + rl(v, 16)) + (rl(v, 32) + rl(v, 48));

        const float g = fmaf(w, __builtin_amdgcn_rcpf(sum), DETC);
        __builtin_nontemporal_store(g, gamma_out + (size_t)i * K + lane);

        accN += g;
        accS  = fmaf(g, u_s, accS);
        // reuse the SGPR row values (no memory re-read)
        accM[0]  = fmaf(g, s00, accM[0]);  accM[1]  = fmaf(g, s01, accM[1]);
        accM[2]  = fmaf(g, s02, accM[2]);  accM[3]  = fmaf(g, s03, accM[3]);
        accM[4]  = fmaf(g, s04, accM[4]);  accM[5]  = fmaf(g, s05, accM[5]);
        accM[6]  = fmaf(g, s06, accM[6]);  accM[7]  = fmaf(g, s07, accM[7]);
        accM[8]  = fmaf(g, s08, accM[8]);  accM[9]  = fmaf(g, s09, accM[9]);
        accM[10] = fmaf(g, s10, accM[10]); accM[11] = fmaf(g, s11, accM[11]);
        accM[12] = fmaf(g, s12, accM[12]); accM[13] = fmaf(g, s13, accM[13]);
        accM[14] = fmaf(g, s14, accM[14]); accM[15] = fmaf(g, s15, accM[15]);
        accM[16] = fmaf(g, s16, accM[16]); accM[17] = fmaf(g, s17, accM[17]);
        accM[18] = fmaf(g, s18, accM[18]); accM[19] = fmaf(g, s19, accM[19]);
        accM[20] = fmaf(g, s20, accM[20]); accM[21] = fmaf(g, s21, accM[21]);
        accM[22] = fmaf(g, s22, accM[22]); accM[23] = fmaf(g, s23, accM[23]);
        accM[24] = fmaf(g, s24, accM[24]); accM[25] = fmaf(g, s25, accM[25]);
        accM[26] = fmaf(g, s26, accM[26]); accM[27] = fmaf(g, s27, accM[27]);
        accM[28] = fmaf(g, s28, accM[28]); accM[29] = fmaf(g, s29, accM[29]);
        accM[30] = fmaf(g, s30, accM[30]); accM[31] = fmaf(g, s31, accM[31]);
    }

    // ---- block combine in LDS, then one set of striped global atomics ----
    __shared__ float red[WS_FLOATS];   // [0,K) N | [K,2K) S | [2K,..) M[d][k]
    for (int idx = threadIdx.x; idx < WS_FLOATS; idx += NTHREADS) red[idx] = 0.f;
    __syncthreads();

    atomicAdd(&red[lane], accN);
    atomicAdd(&red[K + lane], accS);
#pragma unroll
    for (int d = 0; d < P; ++d) atomicAdd(&red[2 * K + d * K + lane], accM[d]);
    __syncthreads();

    // striped cross-block combine: contention per address = NBLOCKS/NCOPIES
    float* wsc = ws + (size_t)(blockIdx.x & (NCOPIES - 1)) * WS_FLOATS;
    for (int idx = threadIdx.x; idx < WS_FLOATS; idx += NTHREADS)
        atomicAdd(&wsc[idx], red[idx]);
    __syncthreads();   // all this block's global atomics drained

    // ---- decoupled finalize: last block reduces the copies + small outputs ----
    __shared__ int lastf;
    if (threadIdx.x == 0) {
        __threadfence();
        const int c = atomicAdd((int*)(ws + (size_t)NCOPIES * WS_FLOATS), 1);
        lastf = (c == NBLOCKS - 1);
    }
    __syncthreads();
    if (lastf) {
        __threadfence();
        for (int idx = threadIdx.x; idx < WS_FLOATS; idx += NTHREADS) {
            float s = 0.f;
#pragma unroll 4
            for (int c = 0; c < NCOPIES; ++c)
                s += __hip_atomic_load(&ws[(size_t)c * WS_FLOATS + idx],
                                       __ATOMIC_RELAXED, __HIP_MEMORY_SCOPE_AGENT);
            red[idx] = s;
        }
        __syncthreads();

        const int k = threadIdx.x;
        if (k < K) {
            const float Nk = red[k];
            const float S  = red[K + k];
            float* pi_new      = out_tail;
            float* mu_new      = out_tail + K;
            float* log_cov_new = out_tail + K + K * P;

            pi_new[k] = Nk / (float)NPTS;
            const float invN = 1.f / Nk;
            float m2 = 0.f;
#pragma unroll
            for (int d = 0; d < P; ++d) {
                const float md = red[2 * K + d * K + k] * invN;
                mu_new[k * P + d] = md;
                m2 = fmaf(md, md, m2);
            }
            const float cov = (S - Nk * m2) / (32.f * Nk);
            log_cov_new[k] = logf(cov);
        }
    }
}

extern "C" void kernel_launch(void* const* d_in, const int* in_sizes, int n_in,
                              void* d_out, int out_size, void* d_ws, size_t ws_size,
                              hipStream_t stream)
{
    const float* mu_phi      = (const float*)d_in[0];
    const float* log_cov_phi = (const float*)d_in[1];
    const float* pi_k        = (const float*)d_in[2];
    const float* mu_k        = (const float*)d_in[3];
    const float* log_cov_k   = (const float*)d_in[4];
    float* out = (float*)d_out;
    float* ws  = (float*)d_ws;

    hipMemsetAsync(ws, 0, ((size_t)NCOPIES * WS_FLOATS + 1) * sizeof(float), stream);
    em_pass<<<NBLOCKS, NTHREADS, 0, stream>>>(mu_phi, log_cov_phi, pi_k, mu_k,
                                              log_cov_k, out,
                                              out + (size_t)NPTS * K, ws);
}